// Round 15
// baseline (89.685 us; speedup 1.0000x reference)
//
#include <hip/hip_runtime.h>
#include <hip/hip_bf16.h>
#include <math.h>

#define NSEQ 2048
#define NH 8
#define DH 64
#define KP 32
#define DM 512
#define NB 2
#define MROWS (NB * NSEQ)   // 4096
#define SLOT4 144           // key-chunk slots per (b,h): sum_{qt=0}^{31} ceil((qt+1)/4)
#define LOG2E 1.4426950408889634f

typedef short bf16x8 __attribute__((ext_vector_type(8)));
typedef float f32x4  __attribute__((ext_vector_type(4)));

static __constant__ float RZF[KP] = {
    14.134725142f, 21.022039639f, 25.01085758f,  30.424876126f, 32.935061588f,
    37.586178159f, 40.918719012f, 43.327073281f, 48.005150881f, 49.773832478f,
    52.970321478f, 56.446247697f, 59.347044003f, 60.831778525f, 65.112544048f,
    67.079810529f, 69.546401711f, 72.067157674f, 75.704690699f, 77.144840069f,
    79.33737502f,  82.910380854f, 84.735492981f, 87.425274613f, 88.809111208f,
    92.491899271f, 94.651344041f, 95.870634228f, 98.831194218f, 101.317851006f,
    103.72553804f, 105.446623052f};

static __device__ __forceinline__ unsigned short f2bf(float f) {
    unsigned int u = __float_as_uint(f);
    unsigned int r = (u + 0x7FFFu + ((u >> 16) & 1u)) >> 16;   // RNE
    return (unsigned short)r;
}
static __device__ __forceinline__ float bf2f(unsigned short s) {
    return __uint_as_float((unsigned int)s << 16);
}
static __device__ __forceinline__ float exp2q(float x) {      // 2^x, single v_exp
    float r; asm("v_exp_f32 %0, %1" : "=v"(r) : "v"(x)); return r;
}

// async global->LDS, 16B per lane; LDS dest = wave-uniform base + lane*16
static __device__ __forceinline__ void gload16(const void* g, void* l) {
    __builtin_amdgcn_global_load_lds(
        (const __attribute__((address_space(1))) void*)g,
        (__attribute__((address_space(3))) void*)l, 16, 0, 0);
}

// ---------------------------------------------------------------------------
// K0: fused prep. [0,1024) x->bf16; [1024,2048) w transposes; [2048,4096)
// tables with one thread per (idx,p), 32-lane shfl reduce for floor-sum.
// biasK is PRE-MULTIPLIED by log2e (softmax runs in exp2 domain).
// ---------------------------------------------------------------------------
__global__ __launch_bounds__(256) void k_prep(
    const float* __restrict__ x, const float* __restrict__ wq,
    const float* __restrict__ wo, const float* __restrict__ ls,
    const float* __restrict__ ll,
    unsigned short* __restrict__ xb, unsigned short* __restrict__ wqT,
    unsigned short* __restrict__ woT,
    float* __restrict__ cosT, float* __restrict__ sinT, float* __restrict__ biasK)
{
    __shared__ float tile[32][33];
    int bid = blockIdx.x;
    int tid = threadIdx.x;
    if (bid < 1024) {
        int i = bid * 256 + tid;
        float4 a = ((const float4*)x)[2 * i];
        float4 b = ((const float4*)x)[2 * i + 1];
        union { unsigned short s[8]; uint4 u; } pk;
        pk.s[0] = f2bf(a.x); pk.s[1] = f2bf(a.y); pk.s[2] = f2bf(a.z); pk.s[3] = f2bf(a.w);
        pk.s[4] = f2bf(b.x); pk.s[5] = f2bf(b.y); pk.s[6] = f2bf(b.z); pk.s[7] = f2bf(b.w);
        ((uint4*)xb)[i] = pk.u;
    } else if (bid < 2048) {
        const float* src; unsigned short* dst; int R, C, bx, by;
        if (bid < 1792) { src = wq; dst = wqT; R = DM; C = 3 * DM;
                          int ix = bid - 1024; bx = ix % 48; by = ix / 48; }
        else            { src = wo; dst = woT; R = DM; C = DM;
                          int ix = bid - 1792; bx = ix & 15; by = ix >> 4; }
        int x0 = bx << 5, y0 = by << 5;
        int tx = tid & 31, ty = tid >> 5;
#pragma unroll
        for (int i = 0; i < 4; ++i)
            tile[ty + i * 8][tx] = src[(size_t)(y0 + ty + i * 8) * C + x0 + tx];
        __syncthreads();
#pragma unroll
        for (int i = 0; i < 4; ++i)
            dst[(size_t)(x0 + ty + i * 8) * R + y0 + tx] = f2bf(tile[tx][ty + i * 8]);
    } else {
        int item = (bid - 2048) * 256 + tid;
        int p   = item & 31;
        int idx = item >> 5;                // h*NSEQ + t, < 16384
        int h = idx >> 11;
        int t = idx & (NSEQ - 1);
        float scale = expf(ls[h]);
        float tau = log1pf((float)t);
        const float TAUF = 6.2831853071795864769f;
        float g  = RZF[p] / RZF[0];
        float th = (tau * g) * scale;
        cosT[(size_t)idx * KP + p] = cosf(th);
        sinT[(size_t)idx * KP + p] = sinf(th);
        float fl = floorf(th / TAUF);
        fl += __shfl_xor(fl, 1);
        fl += __shfl_xor(fl, 2);
        fl += __shfl_xor(fl, 4);
        fl += __shfl_xor(fl, 8);
        fl += __shfl_xor(fl, 16);
        if (p == 0) biasK[idx] = expf(ll[h]) * (1.0f / 32.0f) * fl * LOG2E;
    }
}

// ---------------------------------------------------------------------------
// K2: MFMA GEMM  xb(4096x512 bf16) @ wqT^T, fused rotation epilogue.
// BM=64, BN=128 -> 768 blocks = 3/CU. DOUBLE-BUFFERED issue-early staging.
// q_rot PRE-SCALED by 0.125*log2e (exp2-domain softmax); k_rot unscaled;
// V -> TRANSPOSED [b][h][dh][n] bf16.
// ---------------------------------------------------------------------------
__global__ __launch_bounds__(256) void k_gemm_qkv(
    const unsigned short* __restrict__ xb, const unsigned short* __restrict__ wt,
    const float* __restrict__ cosT, const float* __restrict__ sinT,
    unsigned short* __restrict__ qrot, unsigned short* __restrict__ krot,
    unsigned short* __restrict__ vtout)
{
    __shared__ char Asm[2][64 * 128];    // 8 KB x2
    __shared__ char Bsm[2][128 * 128];   // 16 KB x2
    int tid = threadIdx.x;
    int w = tid >> 6, lane = tid & 63, g = lane >> 4, c = lane & 15;
    int wm = w >> 1, wn = w & 1;
    int bm = blockIdx.y << 6, bn = blockIdx.x << 7;
    int rin = lane >> 3;
    int csw = ((lane & 7) ^ rin) << 4;

    f32x4 acc[2][4];
#pragma unroll
    for (int mi = 0; mi < 2; ++mi)
#pragma unroll
        for (int ni = 0; ni < 4; ++ni) acc[mi][ni] = (f32x4){0.f, 0.f, 0.f, 0.f};

    const char* Ag = (const char*)xb;
    const char* Bg = (const char*)wt;

    auto stage = [&](int buf, int k0) {
#pragma unroll
        for (int ch = 0; ch < 2; ++ch) {            // A: 8 chunks (64 rows)
            int chA = w * 2 + ch;
            int row = chA * 8 + rin;
            gload16(Ag + ((size_t)(bm + row) * DM + k0) * 2 + csw, Asm[buf] + chA * 1024);
        }
#pragma unroll
        for (int ch = 0; ch < 4; ++ch) {            // B: 16 chunks (128 rows)
            int chB = w * 4 + ch;
            int row = chB * 8 + rin;
            gload16(Bg + ((size_t)(bn + row) * DM + k0) * 2 + csw, Bsm[buf] + chB * 1024);
        }
    };

    stage(0, 0);
    asm volatile("s_waitcnt vmcnt(0)" ::: "memory");
    __syncthreads();
    int cur = 0;

    for (int k0 = 0; k0 < DM; k0 += 64) {
        if (k0 + 64 < DM) stage(cur ^ 1, k0 + 64);   // issue-early
#pragma unroll
        for (int kk = 0; kk < 2; ++kk) {
            bf16x8 af[2], bfr[4];
#pragma unroll
            for (int mi = 0; mi < 2; ++mi) {
                int row = wm * 32 + mi * 16 + c;
                af[mi] = *(const bf16x8*)(Asm[cur] + ((row * 128 + kk * 64 + g * 16) ^ ((row & 7) << 4)));
            }
#pragma unroll
            for (int ni = 0; ni < 4; ++ni) {
                int row = wn * 64 + ni * 16 + c;
                bfr[ni] = *(const bf16x8*)(Bsm[cur] + ((row * 128 + kk * 64 + g * 16) ^ ((row & 7) << 4)));
            }
#pragma unroll
            for (int mi = 0; mi < 2; ++mi)
#pragma unroll
                for (int ni = 0; ni < 4; ++ni)
                    acc[mi][ni] = __builtin_amdgcn_mfma_f32_16x16x32_bf16(
                        af[mi], bfr[ni], acc[mi][ni], 0, 0, 0);
        }
        asm volatile("s_waitcnt vmcnt(0)" ::: "memory");   // drain next-tile DMA
        __syncthreads();
        cur ^= 1;
    }

    int lane_odd = c & 1;
#pragma unroll
    for (int ni = 0; ni < 4; ++ni) {
        int n = bn + wn * 64 + ni * 16 + c;
        int sec = n >> 9;               // 0=q 1=k 2=v
        int dmod = n & 511;
        int h = dmod >> 6, dh = dmod & 63, p = dh >> 1;
        if (sec == 2) {
#pragma unroll
            for (int mi = 0; mi < 2; ++mi) {
                int m0 = bm + wm * 32 + mi * 16 + g * 4;
                int b = m0 >> 11, t0 = m0 & (NSEQ - 1);
                union { unsigned short s[4]; uint2 u; } pk;
                pk.s[0] = f2bf(acc[mi][ni][0]); pk.s[1] = f2bf(acc[mi][ni][1]);
                pk.s[2] = f2bf(acc[mi][ni][2]); pk.s[3] = f2bf(acc[mi][ni][3]);
                *(uint2*)(vtout + ((size_t)(b * NH + h) * DH + dh) * NSEQ + t0) = pk.u;
            }
        } else {
            const float* cb_ = cosT + (size_t)h * NSEQ * KP + p;
            const float* sb_ = sinT + (size_t)h * NSEQ * KP + p;
            unsigned short* dst = (sec == 0) ? qrot : krot;
            float osc = (sec == 0) ? (0.125f * LOG2E) : 1.0f;   // exp2-domain scale
#pragma unroll
            for (int mi = 0; mi < 2; ++mi) {
#pragma unroll
                for (int r = 0; r < 4; ++r) {
                    int m = bm + wm * 32 + mi * 16 + g * 4 + r;
                    int b = m >> 11, t = m & (NSEQ - 1);
                    float val = acc[mi][ni][r];
                    float pv = __shfl_xor(val, 1);
                    float cv = cb_[(size_t)t * KP], sv = sb_[(size_t)t * KP];
                    float o = lane_odd ? (pv * sv + val * cv) : (val * cv - pv * sv);
                    dst[((size_t)(b * NH + h) * NSEQ + t) * DH + dh] = f2bf(o * osc);
                }
            }
        }
    }
}

// ---------------------------------------------------------------------------
// K3: split-K MFMA flash attention (r12 scaffold). QBLK=64, K staged in LDS,
// V FRAGMENTS IN REGISTERS (per-lane global loads issued before the single
// vmcnt(0) drain -- land with the K-DMA, zero extra latency exposure; L2-
// resident via XCD bh mapping). exp2-domain softmax (q and bias pre-scaled
// by log2e). 4-tile chunks, 2304 blocks, heavy-first, cvt_pk P-packing.
// ---------------------------------------------------------------------------
__global__ __launch_bounds__(256, 4) void k_attn(
    const unsigned short* __restrict__ qr, const unsigned short* __restrict__ kr,
    const unsigned short* __restrict__ vt, const float* __restrict__ biasK,
    unsigned short* __restrict__ ao, unsigned short* __restrict__ opart,
    float* __restrict__ mlpart)
{
    __shared__ char Kbuf[8192];                 // [key][dh] bf16, row-swizzled
    __shared__ char Pl[4][2048];                // per-wave [16 q][64 key] bf16
    __shared__ float Bk[64];

    int bid = blockIdx.x;
    int xcd = bid & 7;
    int i   = bid >> 3;             // 0..287
    int bh  = xcd * 2 + (i & 1);
    int slot = (SLOT4 - 1) - (i >> 1);          // heavy-first 0..143
    int b = bh >> 3, h = bh & 7;
    int s = slot, qt = 0, nch;
    for (;;) { nch = (qt + 4) >> 2; if (s < nch) break; s -= nch; ++qt; }
    int ci = s;
    int t0 = ci << 2;
    int t1 = min(t0 + 4, qt + 1);

    int q0 = qt << 6;
    int tid = threadIdx.x;
    int w    = tid >> 6;
    int lane = tid & 63;
    int g    = lane >> 4;
    int c    = lane & 15;
    char* Pb = Pl[w];

    const char* kb  = (const char*)(kr + (size_t)bh * NSEQ * DH);
    const char* vtb = (const char*)(vt + (size_t)bh * DH * NSEQ);
    const unsigned short* qb = qr + (size_t)bh * NSEQ * DH;
    const float* bkrow = biasK + (size_t)h * NSEQ;

    int qg = q0 + (w << 4) + c;     // this lane's softmax row (q = c)

    bf16x8 qf[2];
#pragma unroll
    for (int sl = 0; sl < 2; ++sl)
        qf[sl] = *(const bf16x8*)(qb + (size_t)qg * DH + sl * 32 + g * 8);

    f32x4 oa[4];
#pragma unroll
    for (int dt = 0; dt < 4; ++dt) oa[dt] = (f32x4){0.f, 0.f, 0.f, 0.f};
    float mr = -3.0e38f, lr = 0.0f;

    int rin = lane >> 3;
    int swz = ((lane & 7) ^ rin) << 4;          // pre-swizzled source byte-col

    for (int tile = t0; tile < t1; ++tile) {
        int j0 = tile << 6;
        // ---- stage K via DMA; V fragments -> registers; bias -> LDS ----
#pragma unroll
        for (int ii = 0; ii < 2; ++ii) {
            int ch = w * 2 + ii;
            int row = ch * 8 + rin;
            gload16(kb + (size_t)(j0 + row) * 128 + swz, Kbuf + ch * 1024);
        }
        if (tid < 64) Bk[tid] = bkrow[j0 + tid];
        bf16x8 vr[2][4];
#pragma unroll
        for (int sl = 0; sl < 2; ++sl)
#pragma unroll
            for (int dt = 0; dt < 4; ++dt) {
                int d = dt * 16 + c;
                vr[sl][dt] = *(const bf16x8*)(vtb +
                    (size_t)d * (NSEQ * 2) + j0 * 2 + sl * 64 + g * 16);
            }
        asm volatile("s_waitcnt vmcnt(0)" ::: "memory");   // K-DMA + V regs land
        __syncthreads();

        // ---- S^T = K · Q^T  (q pre-scaled by 0.125*log2e) ----
        f32x4 st[4];
#pragma unroll
        for (int kt = 0; kt < 4; ++kt) st[kt] = (f32x4){0.f, 0.f, 0.f, 0.f};
#pragma unroll
        for (int sl = 0; sl < 2; ++sl) {
#pragma unroll
            for (int kt = 0; kt < 4; ++kt) {
                int row = kt * 16 + c;
                bf16x8 af = *(const bf16x8*)(Kbuf +
                    ((row * 128 + sl * 64 + g * 16) ^ ((row & 7) << 4)));
                st[kt] = __builtin_amdgcn_mfma_f32_16x16x32_bf16(af, qf[sl], st[kt], 0, 0, 0);
            }
        }

        // ---- bias + causal mask (log2 domain) ----
        bool diagT = (tile == qt);
        float sv[16];
#pragma unroll
        for (int kt = 0; kt < 4; ++kt) {
#pragma unroll
            for (int r4 = 0; r4 < 4; ++r4) {
                int ki = kt * 16 + g * 4 + r4;
                float vl = st[kt][r4] + Bk[ki];
                if (diagT && (j0 + ki > qg)) vl = -3.0e38f;
                sv[kt * 4 + r4] = vl;
            }
        }

        // ---- online softmax, exp2 domain, defer-max (8 nats = 11.54 bits) ----
        float m16 = sv[0];
#pragma unroll
        for (int ii = 1; ii < 16; ++ii) m16 = fmaxf(m16, sv[ii]);
        m16 = fmaxf(m16, __shfl_xor(m16, 16));
        m16 = fmaxf(m16, __shfl_xor(m16, 32));
        if (__any(m16 > mr + 11.5f)) {
            float mt = fmaxf(mr, m16);
            float corr = exp2q(mr - mt);
            mr = mt;
            lr *= corr;
            float corrO[4];
#pragma unroll
            for (int r4 = 0; r4 < 4; ++r4) corrO[r4] = __shfl(corr, g * 4 + r4);
#pragma unroll
            for (int dt = 0; dt < 4; ++dt)
#pragma unroll
                for (int r4 = 0; r4 < 4; ++r4) oa[dt][r4] *= corrO[r4];
        }
        float psum = 0.0f;
        unsigned int pw[8];
#pragma unroll
        for (int ii = 0; ii < 8; ++ii) {
            float p0 = exp2q(sv[2 * ii]     - mr);
            float p1 = exp2q(sv[2 * ii + 1] - mr);
            psum += p0 + p1;
            asm("v_cvt_pk_bf16_f32 %0, %1, %2" : "=v"(pw[ii]) : "v"(p0), "v"(p1));
        }
        lr += psum;

        // ---- P (bf16) -> per-wave LDS: [q=c][key] ----
#pragma unroll
        for (int kt = 0; kt < 4; ++kt) {
            uint2 u2; u2.x = pw[2 * kt]; u2.y = pw[2 * kt + 1];
            *(uint2*)(Pb + ((c * 128 + kt * 32 + g * 8) ^ ((c & 7) << 4))) = u2;
        }

        // ---- O += P · V  (V from registers) ----
#pragma unroll
        for (int sl = 0; sl < 2; ++sl) {
            bf16x8 pa = *(const bf16x8*)(Pb + ((c * 128 + sl * 64 + g * 16) ^ ((c & 7) << 4)));
#pragma unroll
            for (int dt = 0; dt < 4; ++dt)
                oa[dt] = __builtin_amdgcn_mfma_f32_16x16x32_bf16(pa, vr[sl][dt], oa[dt], 0, 0, 0);
        }
        __syncthreads();   // all waves done reading Kbuf before next stage
    }

    // ---- epilogue: reduce l; lane holds O[q=g*4+r4][d=dt*16+c] ----
    lr += __shfl_xor(lr, 16);
    lr += __shfl_xor(lr, 32);
    if (nch == 1) {     // qt 0..3: single chunk -> final normalized output
        float inv = 1.0f / lr;
        float invO[4];
#pragma unroll
        for (int r4 = 0; r4 < 4; ++r4) invO[r4] = __shfl(inv, g * 4 + r4);
#pragma unroll
        for (int dt = 0; dt < 4; ++dt)
#pragma unroll
            for (int r4 = 0; r4 < 4; ++r4) {
                int row = q0 + (w << 4) + g * 4 + r4;
                ao[((size_t)b * NSEQ + row) * DM + h * DH + dt * 16 + c] =
                    f2bf(oa[dt][r4] * invO[r4]);
            }
    } else {
        size_t obase = ((size_t)bh * SLOT4 + slot) * (64 * 64);
#pragma unroll
        for (int dt = 0; dt < 4; ++dt)
#pragma unroll
            for (int r4 = 0; r4 < 4; ++r4) {
                int row = (w << 4) + g * 4 + r4;     // row within block
                opart[obase + row * 64 + dt * 16 + c] = f2bf(oa[dt][r4]);
            }
        if (g == 0) {   // row = w*16 + c  (mr stored in log2 domain -- merge uses exp2)
            size_t mb = (((size_t)bh * SLOT4 + slot) * 64 + (w << 4) + c) * 2;
            mlpart[mb]     = mr;
            mlpart[mb + 1] = lr;
        }
    }
}

// ---------------------------------------------------------------------------
// K3b: phase-2 merge for qt >= 4 (2..8 chunks). Grid (28, 16bh), 256 thr.
// m values are in log2 domain -> weights use exp2.
// ---------------------------------------------------------------------------
__global__ __launch_bounds__(256) void k_merge(
    const unsigned short* __restrict__ opart, const float* __restrict__ mlpart,
    unsigned short* __restrict__ ao)
{
    int bh = blockIdx.y;
    int b = bh >> 3, h = bh & 7;
    int qt = 4 + blockIdx.x;              // 4..31
    int nch = (qt + 4) >> 2;              // 2..8
    int slot0 = 0;
    for (int q = 0; q < qt; ++q) slot0 += (q + 4) >> 2;
    int tid = threadIdx.x;
    int row = tid >> 2;                   // 0..63
    int d0 = (tid & 3) << 4;              // 0,16,32,48

    size_t pbase = ((size_t)bh * SLOT4 + slot0) * 4096 + row * 64 + d0;
    size_t mbase = (((size_t)bh * SLOT4 + slot0) * 64 + row) * 2;

    float M = -3.0e38f;
#pragma unroll
    for (int cc = 0; cc < 8; ++cc)
        if (cc < nch) M = fmaxf(M, mlpart[mbase + (size_t)cc * 128]);

    float L = 0.0f;
    float o[16];
#pragma unroll
    for (int ii = 0; ii < 16; ++ii) o[ii] = 0.0f;
#pragma unroll
    for (int cc = 0; cc < 8; ++cc) {
        if (cc < nch) {
            float mc = mlpart[mbase + (size_t)cc * 128];
            float lc = mlpart[mbase + (size_t)cc * 128 + 1];
            float wgt = exp2f(mc - M);
            L += lc * wgt;
            union { uint4 u; unsigned short sh[8]; } lo, hi;
            lo.u = *(const uint4*)(opart + pbase + (size_t)cc * 4096);
            hi.u = *(const uint4*)(opart + pbase + (size_t)cc * 4096 + 8);
#pragma unroll
            for (int ii = 0; ii < 8; ++ii) {
                o[ii]     += bf2f(lo.sh[ii]) * wgt;
                o[ii + 8] += bf2f(hi.sh[ii]) * wgt;
            }
        }
    }
    float invL = 1.0f / L;
    int grow = (qt << 6) + row;
    unsigned short* dst = ao + ((size_t)b * NSEQ + grow) * DM + h * DH + d0;
    union { unsigned short sh[8]; uint4 u; } p0, p1;
#pragma unroll
    for (int ii = 0; ii < 8; ++ii) {
        p0.sh[ii] = f2bf(o[ii] * invL);
        p1.sh[ii] = f2bf(o[ii + 8] * invL);
    }
    *(uint4*)dst = p0.u;
    *(uint4*)(dst + 8) = p1.u;
}

// ---------------------------------------------------------------------------
// K4: MFMA GEMM  aob(4096x512 bf16) @ woT^T -> f32 out.
// BM=64, BN=64 -> 512 blocks = 2/CU. Waves 2x2, each 32x32.
// ---------------------------------------------------------------------------
__global__ __launch_bounds__(256) void k_gemm_out(
    const unsigned short* __restrict__ aob, const unsigned short* __restrict__ wt,
    float* __restrict__ out)
{
    __shared__ char Asm[64 * 128];    // 8 KB
    __shared__ char Bsm[64 * 128];    // 8 KB
    int tid = threadIdx.x;
    int w = tid >> 6, lane = tid & 63, g = lane >> 4, c = lane & 15;
    int wm = w >> 1, wn = w & 1;
    int bm = blockIdx.y << 6, bn = blockIdx.x << 6;
    int rin = lane >> 3;
    int csw = ((lane & 7) ^ rin) << 4;

    f32x4 acc[2][2];
#pragma unroll
    for (int mi = 0; mi < 2; ++mi)
#pragma unroll
        for (int ni = 0; ni < 2; ++ni) acc[mi][ni] = (f32x4){0.f, 0.f, 0.f, 0.f};

    const char* Ag = (const char*)aob;
    const char* Bg = (const char*)wt;

    for (int k0 = 0; k0 < DM; k0 += 64) {
        __syncthreads();
#pragma unroll
        for (int ch = 0; ch < 2; ++ch) {            // A: 8 chunks (64 rows)
            int chA = w * 2 + ch;
            int row = chA * 8 + rin;
            gload16(Ag + ((size_t)(bm + row) * DM + k0) * 2 + csw, Asm + chA * 1024);
        }
#pragma unroll
        for (int ch = 0; ch < 2; ++ch) {            // B: 8 chunks (64 rows)
            int chB = w * 2 + ch;
            int row = chB * 8 + rin;
            gload16(Bg + ((size_t)(bn + row) * DM + k0) * 2 + csw, Bsm + chB * 1024);
        }
        asm volatile("s_waitcnt vmcnt(0)" ::: "memory");
        __syncthreads();
#pragma unroll
        for (int kk = 0; kk < 2; ++kk) {
            bf16x8 af[2], bfr[2];
#pragma unroll
            for (int mi = 0; mi < 2; ++mi) {
                int row = wm * 32 + mi * 16 + c;
                af[mi] = *(const bf16x8*)(Asm + ((row * 128 + kk * 64 + g * 16) ^ ((row & 7) << 4)));
            }
#pragma unroll
            for (int ni = 0; ni < 2; ++ni) {
                int row = wn * 32 + ni * 16 + c;
                bfr[ni] = *(const bf16x8*)(Bsm + ((row * 128 + kk * 64 + g * 16) ^ ((row & 7) << 4)));
            }
#pragma unroll
            for (int mi = 0; mi < 2; ++mi)
#pragma unroll
                for (int ni = 0; ni < 2; ++ni)
                    acc[mi][ni] = __builtin_amdgcn_mfma_f32_16x16x32_bf16(
                        af[mi], bfr[ni], acc[mi][ni], 0, 0, 0);
        }
    }

#pragma unroll
    for (int ni = 0; ni < 2; ++ni) {
        int n = bn + wn * 32 + ni * 16 + c;
#pragma unroll
        for (int mi = 0; mi < 2; ++mi)
#pragma unroll
            for (int r = 0; r < 4; ++r) {
                int m = bm + wm * 32 + mi * 16 + g * 4 + r;
                out[(size_t)m * DM + n] = acc[mi][ni][r];
            }
    }
}

// ---------------------------------------------------------------------------
extern "C" void kernel_launch(void* const* d_in, const int* in_sizes, int n_in,
                              void* d_out, int out_size, void* d_ws, size_t ws_size,
                              hipStream_t stream)
{
    const float* x  = (const float*)d_in[0];
    const float* wq = (const float*)d_in[1];
    const float* wo = (const float*)d_in[2];
    const float* ls = (const float*)d_in[3];
    const float* ll = (const float*)d_in[4];
    float* out = (float*)d_out;

    char* ws = (char*)d_ws;
    size_t off = 0;
    float* cosT  = (float*)(ws + off); off += (size_t)NH * NSEQ * KP * 4;        // 2 MB
    float* sinT  = (float*)(ws + off); off += (size_t)NH * NSEQ * KP * 4;        // 2 MB
    float* biasK = (float*)(ws + off); off += (size_t)NH * NSEQ * 4;             // 64 KB
    unsigned short* xb  = (unsigned short*)(ws + off); off += (size_t)MROWS * DM * 2;      // 4 MB
    unsigned short* wqT = (unsigned short*)(ws + off); off += (size_t)DM * 3 * DM * 2;     // 1.5 MB
    unsigned short* woT = (unsigned short*)(ws + off); off += (size_t)DM * DM * 2;         // 0.5 MB
    unsigned short* qbf = (unsigned short*)(ws + off); off += (size_t)MROWS * DM * 2;      // 4 MB
    unsigned short* kbf = (unsigned short*)(ws + off); off += (size_t)MROWS * DM * 2;      // 4 MB
    unsigned short* vtb = (unsigned short*)(ws + off); off += (size_t)MROWS * DM * 2;      // 4 MB
    unsigned short* aob = (unsigned short*)(ws + off); off += (size_t)MROWS * DM * 2;      // 4 MB
    unsigned short* opart = (unsigned short*)(ws + off);
    off += (size_t)NB * NH * SLOT4 * 64 * 64 * 2;                                // 18.9 MB
    float* mlpart = (float*)(ws + off); off += (size_t)NB * NH * SLOT4 * 64 * 2 * 4; // 1.2 MB

    k_prep<<<4096, 256, 0, stream>>>(x, wq, wo, ls, ll, xb, wqT, woT, cosT, sinT, biasK);
    k_gemm_qkv<<<dim3(3 * DM / 128, MROWS / 64), 256, 0, stream>>>(
        xb, wqT, cosT, sinT, qbf, kbf, vtb);
    k_attn<<<8 * 288, 256, 0, stream>>>(
        qbf, kbf, vtb, biasK, aob, opart, mlpart);
    k_merge<<<dim3(28, NB * NH), 256, 0, stream>>>(opart, mlpart, aob);
    k_gemm_out<<<dim3(DM / 64, MROWS / 64), 256, 0, stream>>>(aob, woT, out);
}

// Round 16
// 88.321 us; speedup vs baseline: 1.0154x; 1.0154x over previous
//
#include <hip/hip_runtime.h>
#include <hip/hip_bf16.h>
#include <math.h>

#define NSEQ 2048
#define NH 8
#define DH 64
#define KP 32
#define DM 512
#define NB 2
#define MROWS (NB * NSEQ)   // 4096
#define SLOT4 144           // key-chunk slots per (b,h): sum_{qt=0}^{31} ceil((qt+1)/4)
#define LOG2E 1.4426950408889634f

typedef short bf16x8 __attribute__((ext_vector_type(8)));
typedef float f32x4  __attribute__((ext_vector_type(4)));

static __constant__ float RZF[KP] = {
    14.134725142f, 21.022039639f, 25.01085758f,  30.424876126f, 32.935061588f,
    37.586178159f, 40.918719012f, 43.327073281f, 48.005150881f, 49.773832478f,
    52.970321478f, 56.446247697f, 59.347044003f, 60.831778525f, 65.112544048f,
    67.079810529f, 69.546401711f, 72.067157674f, 75.704690699f, 77.144840069f,
    79.33737502f,  82.910380854f, 84.735492981f, 87.425274613f, 88.809111208f,
    92.491899271f, 94.651344041f, 95.870634228f, 98.831194218f, 101.317851006f,
    103.72553804f, 105.446623052f};

static __device__ __forceinline__ unsigned short f2bf(float f) {
    unsigned int u = __float_as_uint(f);
    unsigned int r = (u + 0x7FFFu + ((u >> 16) & 1u)) >> 16;   // RNE
    return (unsigned short)r;
}
static __device__ __forceinline__ float bf2f(unsigned short s) {
    return __uint_as_float((unsigned int)s << 16);
}
static __device__ __forceinline__ float exp2q(float x) {      // 2^x, single v_exp
    float r; asm("v_exp_f32 %0, %1" : "=v"(r) : "v"(x)); return r;
}

// async global->LDS, 16B per lane; LDS dest = wave-uniform base + lane*16
static __device__ __forceinline__ void gload16(const void* g, void* l) {
    __builtin_amdgcn_global_load_lds(
        (const __attribute__((address_space(1))) void*)g,
        (__attribute__((address_space(3))) void*)l, 16, 0, 0);
}

// ---------------------------------------------------------------------------
// K0: fused prep. [0,1024) x->bf16; [1024,2048) w transposes; [2048,4096)
// tables with one thread per (idx,p), 32-lane shfl reduce for floor-sum.
// biasK is PRE-MULTIPLIED by log2e (softmax runs in exp2 domain).
// ---------------------------------------------------------------------------
__global__ __launch_bounds__(256) void k_prep(
    const float* __restrict__ x, const float* __restrict__ wq,
    const float* __restrict__ wo, const float* __restrict__ ls,
    const float* __restrict__ ll,
    unsigned short* __restrict__ xb, unsigned short* __restrict__ wqT,
    unsigned short* __restrict__ woT,
    float* __restrict__ cosT, float* __restrict__ sinT, float* __restrict__ biasK)
{
    __shared__ float tile[32][33];
    int bid = blockIdx.x;
    int tid = threadIdx.x;
    if (bid < 1024) {
        int i = bid * 256 + tid;
        float4 a = ((const float4*)x)[2 * i];
        float4 b = ((const float4*)x)[2 * i + 1];
        union { unsigned short s[8]; uint4 u; } pk;
        pk.s[0] = f2bf(a.x); pk.s[1] = f2bf(a.y); pk.s[2] = f2bf(a.z); pk.s[3] = f2bf(a.w);
        pk.s[4] = f2bf(b.x); pk.s[5] = f2bf(b.y); pk.s[6] = f2bf(b.z); pk.s[7] = f2bf(b.w);
        ((uint4*)xb)[i] = pk.u;
    } else if (bid < 2048) {
        const float* src; unsigned short* dst; int R, C, bx, by;
        if (bid < 1792) { src = wq; dst = wqT; R = DM; C = 3 * DM;
                          int ix = bid - 1024; bx = ix % 48; by = ix / 48; }
        else            { src = wo; dst = woT; R = DM; C = DM;
                          int ix = bid - 1792; bx = ix & 15; by = ix >> 4; }
        int x0 = bx << 5, y0 = by << 5;
        int tx = tid & 31, ty = tid >> 5;
#pragma unroll
        for (int i = 0; i < 4; ++i)
            tile[ty + i * 8][tx] = src[(size_t)(y0 + ty + i * 8) * C + x0 + tx];
        __syncthreads();
#pragma unroll
        for (int i = 0; i < 4; ++i)
            dst[(size_t)(x0 + ty + i * 8) * R + y0 + tx] = f2bf(tile[tx][ty + i * 8]);
    } else {
        int item = (bid - 2048) * 256 + tid;
        int p   = item & 31;
        int idx = item >> 5;                // h*NSEQ + t, < 16384
        int h = idx >> 11;
        int t = idx & (NSEQ - 1);
        float scale = expf(ls[h]);
        float tau = log1pf((float)t);
        const float TAUF = 6.2831853071795864769f;
        float g  = RZF[p] / RZF[0];
        float th = (tau * g) * scale;
        cosT[(size_t)idx * KP + p] = cosf(th);
        sinT[(size_t)idx * KP + p] = sinf(th);
        float fl = floorf(th / TAUF);
        fl += __shfl_xor(fl, 1);
        fl += __shfl_xor(fl, 2);
        fl += __shfl_xor(fl, 4);
        fl += __shfl_xor(fl, 8);
        fl += __shfl_xor(fl, 16);
        if (p == 0) biasK[idx] = expf(ll[h]) * (1.0f / 32.0f) * fl * LOG2E;
    }
}

// ---------------------------------------------------------------------------
// K2: MFMA GEMM  xb(4096x512 bf16) @ wqT^T, fused rotation epilogue.
// BM=64, BN=128 -> 768 blocks = 3/CU. DOUBLE-BUFFERED issue-early staging.
// q_rot PRE-SCALED by 0.125*log2e (exp2-domain softmax); k_rot unscaled;
// V -> TRANSPOSED [b][h][dh][n] bf16.
// ---------------------------------------------------------------------------
__global__ __launch_bounds__(256) void k_gemm_qkv(
    const unsigned short* __restrict__ xb, const unsigned short* __restrict__ wt,
    const float* __restrict__ cosT, const float* __restrict__ sinT,
    unsigned short* __restrict__ qrot, unsigned short* __restrict__ krot,
    unsigned short* __restrict__ vtout)
{
    __shared__ char Asm[2][64 * 128];    // 8 KB x2
    __shared__ char Bsm[2][128 * 128];   // 16 KB x2
    int tid = threadIdx.x;
    int w = tid >> 6, lane = tid & 63, g = lane >> 4, c = lane & 15;
    int wm = w >> 1, wn = w & 1;
    int bm = blockIdx.y << 6, bn = blockIdx.x << 7;
    int rin = lane >> 3;
    int csw = ((lane & 7) ^ rin) << 4;

    f32x4 acc[2][4];
#pragma unroll
    for (int mi = 0; mi < 2; ++mi)
#pragma unroll
        for (int ni = 0; ni < 4; ++ni) acc[mi][ni] = (f32x4){0.f, 0.f, 0.f, 0.f};

    const char* Ag = (const char*)xb;
    const char* Bg = (const char*)wt;

    auto stage = [&](int buf, int k0) {
#pragma unroll
        for (int ch = 0; ch < 2; ++ch) {            // A: 8 chunks (64 rows)
            int chA = w * 2 + ch;
            int row = chA * 8 + rin;
            gload16(Ag + ((size_t)(bm + row) * DM + k0) * 2 + csw, Asm[buf] + chA * 1024);
        }
#pragma unroll
        for (int ch = 0; ch < 4; ++ch) {            // B: 16 chunks (128 rows)
            int chB = w * 4 + ch;
            int row = chB * 8 + rin;
            gload16(Bg + ((size_t)(bn + row) * DM + k0) * 2 + csw, Bsm[buf] + chB * 1024);
        }
    };

    stage(0, 0);
    asm volatile("s_waitcnt vmcnt(0)" ::: "memory");
    __syncthreads();
    int cur = 0;

    for (int k0 = 0; k0 < DM; k0 += 64) {
        if (k0 + 64 < DM) stage(cur ^ 1, k0 + 64);   // issue-early
#pragma unroll
        for (int kk = 0; kk < 2; ++kk) {
            bf16x8 af[2], bfr[4];
#pragma unroll
            for (int mi = 0; mi < 2; ++mi) {
                int row = wm * 32 + mi * 16 + c;
                af[mi] = *(const bf16x8*)(Asm[cur] + ((row * 128 + kk * 64 + g * 16) ^ ((row & 7) << 4)));
            }
#pragma unroll
            for (int ni = 0; ni < 4; ++ni) {
                int row = wn * 64 + ni * 16 + c;
                bfr[ni] = *(const bf16x8*)(Bsm[cur] + ((row * 128 + kk * 64 + g * 16) ^ ((row & 7) << 4)));
            }
#pragma unroll
            for (int mi = 0; mi < 2; ++mi)
#pragma unroll
                for (int ni = 0; ni < 4; ++ni)
                    acc[mi][ni] = __builtin_amdgcn_mfma_f32_16x16x32_bf16(
                        af[mi], bfr[ni], acc[mi][ni], 0, 0, 0);
        }
        asm volatile("s_waitcnt vmcnt(0)" ::: "memory");   // drain next-tile DMA
        __syncthreads();
        cur ^= 1;
    }

    int lane_odd = c & 1;
#pragma unroll
    for (int ni = 0; ni < 4; ++ni) {
        int n = bn + wn * 64 + ni * 16 + c;
        int sec = n >> 9;               // 0=q 1=k 2=v
        int dmod = n & 511;
        int h = dmod >> 6, dh = dmod & 63, p = dh >> 1;
        if (sec == 2) {
#pragma unroll
            for (int mi = 0; mi < 2; ++mi) {
                int m0 = bm + wm * 32 + mi * 16 + g * 4;
                int b = m0 >> 11, t0 = m0 & (NSEQ - 1);
                union { unsigned short s[4]; uint2 u; } pk;
                pk.s[0] = f2bf(acc[mi][ni][0]); pk.s[1] = f2bf(acc[mi][ni][1]);
                pk.s[2] = f2bf(acc[mi][ni][2]); pk.s[3] = f2bf(acc[mi][ni][3]);
                *(uint2*)(vtout + ((size_t)(b * NH + h) * DH + dh) * NSEQ + t0) = pk.u;
            }
        } else {
            const float* cb_ = cosT + (size_t)h * NSEQ * KP + p;
            const float* sb_ = sinT + (size_t)h * NSEQ * KP + p;
            unsigned short* dst = (sec == 0) ? qrot : krot;
            float osc = (sec == 0) ? (0.125f * LOG2E) : 1.0f;   // exp2-domain scale
#pragma unroll
            for (int mi = 0; mi < 2; ++mi) {
#pragma unroll
                for (int r = 0; r < 4; ++r) {
                    int m = bm + wm * 32 + mi * 16 + g * 4 + r;
                    int b = m >> 11, t = m & (NSEQ - 1);
                    float val = acc[mi][ni][r];
                    float pv = __shfl_xor(val, 1);
                    float cv = cb_[(size_t)t * KP], sv = sb_[(size_t)t * KP];
                    float o = lane_odd ? (pv * sv + val * cv) : (val * cv - pv * sv);
                    dst[((size_t)(b * NH + h) * NSEQ + t) * DH + dh] = f2bf(o * osc);
                }
            }
        }
    }
}

// ---------------------------------------------------------------------------
// K3: split-K MFMA flash attention. QBLK=64, K staged in LDS, V fragments in
// registers (per-lane global loads before the single vmcnt(0) drain; L2-
// resident via XCD bh mapping). exp2-domain softmax. NO min-wave
// launch_bounds: r15's (256,4) forced VGPR=64 and spilled (2x regression) --
// let the allocator pick ~110-130 naturally.
// ---------------------------------------------------------------------------
__global__ __launch_bounds__(256) void k_attn(
    const unsigned short* __restrict__ qr, const unsigned short* __restrict__ kr,
    const unsigned short* __restrict__ vt, const float* __restrict__ biasK,
    unsigned short* __restrict__ ao, unsigned short* __restrict__ opart,
    float* __restrict__ mlpart)
{
    __shared__ char Kbuf[8192];                 // [key][dh] bf16, row-swizzled
    __shared__ char Pl[4][2048];                // per-wave [16 q][64 key] bf16
    __shared__ float Bk[64];

    int bid = blockIdx.x;
    int xcd = bid & 7;
    int i   = bid >> 3;             // 0..287
    int bh  = xcd * 2 + (i & 1);
    int slot = (SLOT4 - 1) - (i >> 1);          // heavy-first 0..143
    int b = bh >> 3, h = bh & 7;
    int s = slot, qt = 0, nch;
    for (;;) { nch = (qt + 4) >> 2; if (s < nch) break; s -= nch; ++qt; }
    int ci = s;
    int t0 = ci << 2;
    int t1 = min(t0 + 4, qt + 1);

    int q0 = qt << 6;
    int tid = threadIdx.x;
    int w    = tid >> 6;
    int lane = tid & 63;
    int g    = lane >> 4;
    int c    = lane & 15;
    char* Pb = Pl[w];

    const char* kb  = (const char*)(kr + (size_t)bh * NSEQ * DH);
    const char* vtb = (const char*)(vt + (size_t)bh * DH * NSEQ);
    const unsigned short* qb = qr + (size_t)bh * NSEQ * DH;
    const float* bkrow = biasK + (size_t)h * NSEQ;

    int qg = q0 + (w << 4) + c;     // this lane's softmax row (q = c)

    bf16x8 qf[2];
#pragma unroll
    for (int sl = 0; sl < 2; ++sl)
        qf[sl] = *(const bf16x8*)(qb + (size_t)qg * DH + sl * 32 + g * 8);

    f32x4 oa[4];
#pragma unroll
    for (int dt = 0; dt < 4; ++dt) oa[dt] = (f32x4){0.f, 0.f, 0.f, 0.f};
    float mr = -3.0e38f, lr = 0.0f;

    int rin = lane >> 3;
    int swz = ((lane & 7) ^ rin) << 4;          // pre-swizzled source byte-col

    for (int tile = t0; tile < t1; ++tile) {
        int j0 = tile << 6;
        // ---- stage K via DMA; V fragments -> registers; bias -> LDS ----
#pragma unroll
        for (int ii = 0; ii < 2; ++ii) {
            int ch = w * 2 + ii;
            int row = ch * 8 + rin;
            gload16(kb + (size_t)(j0 + row) * 128 + swz, Kbuf + ch * 1024);
        }
        if (tid < 64) Bk[tid] = bkrow[j0 + tid];
        bf16x8 vr[2][4];
#pragma unroll
        for (int sl = 0; sl < 2; ++sl)
#pragma unroll
            for (int dt = 0; dt < 4; ++dt) {
                int d = dt * 16 + c;
                vr[sl][dt] = *(const bf16x8*)(vtb +
                    (size_t)d * (NSEQ * 2) + j0 * 2 + sl * 64 + g * 16);
            }
        asm volatile("s_waitcnt vmcnt(0)" ::: "memory");   // K-DMA + V regs land
        __syncthreads();

        // ---- S^T = K · Q^T  (q pre-scaled by 0.125*log2e) ----
        f32x4 st[4];
#pragma unroll
        for (int kt = 0; kt < 4; ++kt) st[kt] = (f32x4){0.f, 0.f, 0.f, 0.f};
#pragma unroll
        for (int sl = 0; sl < 2; ++sl) {
#pragma unroll
            for (int kt = 0; kt < 4; ++kt) {
                int row = kt * 16 + c;
                bf16x8 af = *(const bf16x8*)(Kbuf +
                    ((row * 128 + sl * 64 + g * 16) ^ ((row & 7) << 4)));
                st[kt] = __builtin_amdgcn_mfma_f32_16x16x32_bf16(af, qf[sl], st[kt], 0, 0, 0);
            }
        }

        // ---- bias + causal mask (log2 domain) ----
        bool diagT = (tile == qt);
        float sv[16];
#pragma unroll
        for (int kt = 0; kt < 4; ++kt) {
#pragma unroll
            for (int r4 = 0; r4 < 4; ++r4) {
                int ki = kt * 16 + g * 4 + r4;
                float vl = st[kt][r4] + Bk[ki];
                if (diagT && (j0 + ki > qg)) vl = -3.0e38f;
                sv[kt * 4 + r4] = vl;
            }
        }

        // ---- online softmax, exp2 domain, defer-max (8 nats = 11.54 bits) ----
        float m16 = sv[0];
#pragma unroll
        for (int ii = 1; ii < 16; ++ii) m16 = fmaxf(m16, sv[ii]);
        m16 = fmaxf(m16, __shfl_xor(m16, 16));
        m16 = fmaxf(m16, __shfl_xor(m16, 32));
        if (__any(m16 > mr + 11.5f)) {
            float mt = fmaxf(mr, m16);
            float corr = exp2q(mr - mt);
            mr = mt;
            lr *= corr;
            float corrO[4];
#pragma unroll
            for (int r4 = 0; r4 < 4; ++r4) corrO[r4] = __shfl(corr, g * 4 + r4);
#pragma unroll
            for (int dt = 0; dt < 4; ++dt)
#pragma unroll
                for (int r4 = 0; r4 < 4; ++r4) oa[dt][r4] *= corrO[r4];
        }
        float psum = 0.0f;
        unsigned int pw[8];
#pragma unroll
        for (int ii = 0; ii < 8; ++ii) {
            float p0 = exp2q(sv[2 * ii]     - mr);
            float p1 = exp2q(sv[2 * ii + 1] - mr);
            psum += p0 + p1;
            asm("v_cvt_pk_bf16_f32 %0, %1, %2" : "=v"(pw[ii]) : "v"(p0), "v"(p1));
        }
        lr += psum;

        // ---- P (bf16) -> per-wave LDS: [q=c][key] ----
#pragma unroll
        for (int kt = 0; kt < 4; ++kt) {
            uint2 u2; u2.x = pw[2 * kt]; u2.y = pw[2 * kt + 1];
            *(uint2*)(Pb + ((c * 128 + kt * 32 + g * 8) ^ ((c & 7) << 4))) = u2;
        }

        // ---- O += P · V  (V from registers) ----
#pragma unroll
        for (int sl = 0; sl < 2; ++sl) {
            bf16x8 pa = *(const bf16x8*)(Pb + ((c * 128 + sl * 64 + g * 16) ^ ((c & 7) << 4)));
#pragma unroll
            for (int dt = 0; dt < 4; ++dt)
                oa[dt] = __builtin_amdgcn_mfma_f32_16x16x32_bf16(pa, vr[sl][dt], oa[dt], 0, 0, 0);
        }
        __syncthreads();   // all waves done reading Kbuf before next stage
    }

    // ---- epilogue: reduce l; lane holds O[q=g*4+r4][d=dt*16+c] ----
    lr += __shfl_xor(lr, 16);
    lr += __shfl_xor(lr, 32);
    if (nch == 1) {     // qt 0..3: single chunk -> final normalized output
        float inv = 1.0f / lr;
        float invO[4];
#pragma unroll
        for (int r4 = 0; r4 < 4; ++r4) invO[r4] = __shfl(inv, g * 4 + r4);
#pragma unroll
        for (int dt = 0; dt < 4; ++dt)
#pragma unroll
            for (int r4 = 0; r4 < 4; ++r4) {
                int row = q0 + (w << 4) + g * 4 + r4;
                ao[((size_t)b * NSEQ + row) * DM + h * DH + dt * 16 + c] =
                    f2bf(oa[dt][r4] * invO[r4]);
            }
    } else {
        size_t obase = ((size_t)bh * SLOT4 + slot) * (64 * 64);
#pragma unroll
        for (int dt = 0; dt < 4; ++dt)
#pragma unroll
            for (int r4 = 0; r4 < 4; ++r4) {
                int row = (w << 4) + g * 4 + r4;     // row within block
                opart[obase + row * 64 + dt * 16 + c] = f2bf(oa[dt][r4]);
            }
        if (g == 0) {   // row = w*16 + c  (mr stored in log2 domain -- merge uses exp2)
            size_t mb = (((size_t)bh * SLOT4 + slot) * 64 + (w << 4) + c) * 2;
            mlpart[mb]     = mr;
            mlpart[mb + 1] = lr;
        }
    }
}

// ---------------------------------------------------------------------------
// K3b: phase-2 merge for qt >= 4 (2..8 chunks). Grid (28, 16bh), 256 thr.
// m values are in log2 domain -> weights use exp2.
// ---------------------------------------------------------------------------
__global__ __launch_bounds__(256) void k_merge(
    const unsigned short* __restrict__ opart, const float* __restrict__ mlpart,
    unsigned short* __restrict__ ao)
{
    int bh = blockIdx.y;
    int b = bh >> 3, h = bh & 7;
    int qt = 4 + blockIdx.x;              // 4..31
    int nch = (qt + 4) >> 2;              // 2..8
    int slot0 = 0;
    for (int q = 0; q < qt; ++q) slot0 += (q + 4) >> 2;
    int tid = threadIdx.x;
    int row = tid >> 2;                   // 0..63
    int d0 = (tid & 3) << 4;              // 0,16,32,48

    size_t pbase = ((size_t)bh * SLOT4 + slot0) * 4096 + row * 64 + d0;
    size_t mbase = (((size_t)bh * SLOT4 + slot0) * 64 + row) * 2;

    float M = -3.0e38f;
#pragma unroll
    for (int cc = 0; cc < 8; ++cc)
        if (cc < nch) M = fmaxf(M, mlpart[mbase + (size_t)cc * 128]);

    float L = 0.0f;
    float o[16];
#pragma unroll
    for (int ii = 0; ii < 16; ++ii) o[ii] = 0.0f;
#pragma unroll
    for (int cc = 0; cc < 8; ++cc) {
        if (cc < nch) {
            float mc = mlpart[mbase + (size_t)cc * 128];
            float lc = mlpart[mbase + (size_t)cc * 128 + 1];
            float wgt = exp2f(mc - M);
            L += lc * wgt;
            union { uint4 u; unsigned short sh[8]; } lo, hi;
            lo.u = *(const uint4*)(opart + pbase + (size_t)cc * 4096);
            hi.u = *(const uint4*)(opart + pbase + (size_t)cc * 4096 + 8);
#pragma unroll
            for (int ii = 0; ii < 8; ++ii) {
                o[ii]     += bf2f(lo.sh[ii]) * wgt;
                o[ii + 8] += bf2f(hi.sh[ii]) * wgt;
            }
        }
    }
    float invL = 1.0f / L;
    int grow = (qt << 6) + row;
    unsigned short* dst = ao + ((size_t)b * NSEQ + grow) * DM + h * DH + d0;
    union { unsigned short sh[8]; uint4 u; } p0, p1;
#pragma unroll
    for (int ii = 0; ii < 8; ++ii) {
        p0.sh[ii] = f2bf(o[ii] * invL);
        p1.sh[ii] = f2bf(o[ii + 8] * invL);
    }
    *(uint4*)dst = p0.u;
    *(uint4*)(dst + 8) = p1.u;
}

// ---------------------------------------------------------------------------
// K4: MFMA GEMM  aob(4096x512 bf16) @ woT^T -> f32 out.
// BM=64, BN=64 -> 512 blocks = 2/CU. Waves 2x2, each 32x32.
// ---------------------------------------------------------------------------
__global__ __launch_bounds__(256) void k_gemm_out(
    const unsigned short* __restrict__ aob, const unsigned short* __restrict__ wt,
    float* __restrict__ out)
{
    __shared__ char Asm[64 * 128];    // 8 KB
    __shared__ char Bsm[64 * 128];    // 8 KB
    int tid = threadIdx.x;
    int w = tid >> 6, lane = tid & 63, g = lane >> 4, c = lane & 15;
    int wm = w >> 1, wn = w & 1;
    int bm = blockIdx.y << 6, bn = blockIdx.x << 6;
    int rin = lane >> 3;
    int csw = ((lane & 7) ^ rin) << 4;

    f32x4 acc[2][2];
#pragma unroll
    for (int mi = 0; mi < 2; ++mi)
#pragma unroll
        for (int ni = 0; ni < 2; ++ni) acc[mi][ni] = (f32x4){0.f, 0.f, 0.f, 0.f};

    const char* Ag = (const char*)aob;
    const char* Bg = (const char*)wt;

    for (int k0 = 0; k0 < DM; k0 += 64) {
        __syncthreads();
#pragma unroll
        for (int ch = 0; ch < 2; ++ch) {            // A: 8 chunks (64 rows)
            int chA = w * 2 + ch;
            int row = chA * 8 + rin;
            gload16(Ag + ((size_t)(bm + row) * DM + k0) * 2 + csw, Asm + chA * 1024);
        }
#pragma unroll
        for (int ch = 0; ch < 2; ++ch) {            // B: 8 chunks (64 rows)
            int chB = w * 2 + ch;
            int row = chB * 8 + rin;
            gload16(Bg + ((size_t)(bn + row) * DM + k0) * 2 + csw, Bsm + chB * 1024);
        }
        asm volatile("s_waitcnt vmcnt(0)" ::: "memory");
        __syncthreads();
#pragma unroll
        for (int kk = 0; kk < 2; ++kk) {
            bf16x8 af[2], bfr[2];
#pragma unroll
            for (int mi = 0; mi < 2; ++mi) {
                int row = wm * 32 + mi * 16 + c;
                af[mi] = *(const bf16x8*)(Asm + ((row * 128 + kk * 64 + g * 16) ^ ((row & 7) << 4)));
            }
#pragma unroll
            for (int ni = 0; ni < 2; ++ni) {
                int row = wn * 32 + ni * 16 + c;
                bfr[ni] = *(const bf16x8*)(Bsm + ((row * 128 + kk * 64 + g * 16) ^ ((row & 7) << 4)));
            }
#pragma unroll
            for (int mi = 0; mi < 2; ++mi)
#pragma unroll
                for (int ni = 0; ni < 2; ++ni)
                    acc[mi][ni] = __builtin_amdgcn_mfma_f32_16x16x32_bf16(
                        af[mi], bfr[ni], acc[mi][ni], 0, 0, 0);
        }
    }

#pragma unroll
    for (int ni = 0; ni < 2; ++ni) {
        int n = bn + wn * 32 + ni * 16 + c;
#pragma unroll
        for (int mi = 0; mi < 2; ++mi)
#pragma unroll
            for (int r = 0; r < 4; ++r) {
                int m = bm + wm * 32 + mi * 16 + g * 4 + r;
                out[(size_t)m * DM + n] = acc[mi][ni][r];
            }
    }
}

// ---------------------------------------------------------------------------
extern "C" void kernel_launch(void* const* d_in, const int* in_sizes, int n_in,
                              void* d_out, int out_size, void* d_ws, size_t ws_size,
                              hipStream_t stream)
{
    const float* x  = (const float*)d_in[0];
    const float* wq = (const float*)d_in[1];
    const float* wo = (const float*)d_in[2];
    const float* ls = (const float*)d_in[3];
    const float* ll = (const float*)d_in[4];
    float* out = (float*)d_out;

    char* ws = (char*)d_ws;
    size_t off = 0;
    float* cosT  = (float*)(ws + off); off += (size_t)NH * NSEQ * KP * 4;        // 2 MB
    float* sinT  = (float*)(ws + off); off += (size_t)NH * NSEQ * KP * 4;        // 2 MB
    float* biasK = (float*)(ws + off); off += (size_t)NH * NSEQ * 4;             // 64 KB
    unsigned short* xb  = (unsigned short*)(ws + off); off += (size_t)MROWS * DM * 2;      // 4 MB
    unsigned short* wqT = (unsigned short*)(ws + off); off += (size_t)DM * 3 * DM * 2;     // 1.5 MB
    unsigned short* woT = (unsigned short*)(ws + off); off += (size_t)DM * DM * 2;         // 0.5 MB
    unsigned short* qbf = (unsigned short*)(ws + off); off += (size_t)MROWS * DM * 2;      // 4 MB
    unsigned short* kbf = (unsigned short*)(ws + off); off += (size_t)MROWS * DM * 2;      // 4 MB
    unsigned short* vtb = (unsigned short*)(ws + off); off += (size_t)MROWS * DM * 2;      // 4 MB
    unsigned short* aob = (unsigned short*)(ws + off); off += (size_t)MROWS * DM * 2;      // 4 MB
    unsigned short* opart = (unsigned short*)(ws + off);
    off += (size_t)NB * NH * SLOT4 * 64 * 64 * 2;                                // 18.9 MB
    float* mlpart = (float*)(ws + off); off += (size_t)NB * NH * SLOT4 * 64 * 2 * 4; // 1.2 MB

    k_prep<<<4096, 256, 0, stream>>>(x, wq, wo, ls, ll, xb, wqT, woT, cosT, sinT, biasK);
    k_gemm_qkv<<<dim3(3 * DM / 128, MROWS / 64), 256, 0, stream>>>(
        xb, wqT, cosT, sinT, qbf, kbf, vtb);
    k_attn<<<8 * 288, 256, 0, stream>>>(
        qbf, kbf, vtb, biasK, aob, opart, mlpart);
    k_merge<<<dim3(28, NB * NH), 256, 0, stream>>>(opart, mlpart, aob);
    k_gemm_out<<<dim3(DM / 64, MROWS / 64), 256, 0, stream>>>(aob, woT, out);
}

// Round 17
// 69.351 us; speedup vs baseline: 1.2932x; 1.2735x over previous
//
#include <hip/hip_runtime.h>
#include <hip/hip_bf16.h>
#include <math.h>

#define NSEQ 2048
#define NH 8
#define DH 64
#define KP 32
#define DM 512
#define NB 2
#define MROWS (NB * NSEQ)   // 4096
#define SLOT4 144           // key-chunk slots per (b,h): sum_{qt=0}^{31} ceil((qt+1)/4)
#define LOG2E 1.4426950408889634f

typedef short bf16x8 __attribute__((ext_vector_type(8)));
typedef float f32x4  __attribute__((ext_vector_type(4)));

static __constant__ float RZF[KP] = {
    14.134725142f, 21.022039639f, 25.01085758f,  30.424876126f, 32.935061588f,
    37.586178159f, 40.918719012f, 43.327073281f, 48.005150881f, 49.773832478f,
    52.970321478f, 56.446247697f, 59.347044003f, 60.831778525f, 65.112544048f,
    67.079810529f, 69.546401711f, 72.067157674f, 75.704690699f, 77.144840069f,
    79.33737502f,  82.910380854f, 84.735492981f, 87.425274613f, 88.809111208f,
    92.491899271f, 94.651344041f, 95.870634228f, 98.831194218f, 101.317851006f,
    103.72553804f, 105.446623052f};

static __device__ __forceinline__ unsigned short f2bf(float f) {
    unsigned int u = __float_as_uint(f);
    unsigned int r = (u + 0x7FFFu + ((u >> 16) & 1u)) >> 16;   // RNE
    return (unsigned short)r;
}
static __device__ __forceinline__ float bf2f(unsigned short s) {
    return __uint_as_float((unsigned int)s << 16);
}
static __device__ __forceinline__ float exp2q(float x) {      // 2^x, single v_exp
    float r; asm("v_exp_f32 %0, %1" : "=v"(r) : "v"(x)); return r;
}

// async global->LDS, 16B per lane; LDS dest = wave-uniform base + lane*16
static __device__ __forceinline__ void gload16(const void* g, void* l) {
    __builtin_amdgcn_global_load_lds(
        (const __attribute__((address_space(1))) void*)g,
        (__attribute__((address_space(3))) void*)l, 16, 0, 0);
}

// ---------------------------------------------------------------------------
// K0: fused prep. [0,1024) x->bf16; [1024,2048) w transposes; [2048,4096)
// tables, one thread per (idx,p), 32-lane shfl reduce. biasK scaled by log2e.
// ---------------------------------------------------------------------------
__global__ __launch_bounds__(256) void k_prep(
    const float* __restrict__ x, const float* __restrict__ wq,
    const float* __restrict__ wo, const float* __restrict__ ls,
    const float* __restrict__ ll,
    unsigned short* __restrict__ xb, unsigned short* __restrict__ wqT,
    unsigned short* __restrict__ woT,
    float* __restrict__ cosT, float* __restrict__ sinT, float* __restrict__ biasK)
{
    __shared__ float tile[32][33];
    int bid = blockIdx.x;
    int tid = threadIdx.x;
    if (bid < 1024) {
        int i = bid * 256 + tid;
        float4 a = ((const float4*)x)[2 * i];
        float4 b = ((const float4*)x)[2 * i + 1];
        union { unsigned short s[8]; uint4 u; } pk;
        pk.s[0] = f2bf(a.x); pk.s[1] = f2bf(a.y); pk.s[2] = f2bf(a.z); pk.s[3] = f2bf(a.w);
        pk.s[4] = f2bf(b.x); pk.s[5] = f2bf(b.y); pk.s[6] = f2bf(b.z); pk.s[7] = f2bf(b.w);
        ((uint4*)xb)[i] = pk.u;
    } else if (bid < 2048) {
        const float* src; unsigned short* dst; int R, C, bx, by;
        if (bid < 1792) { src = wq; dst = wqT; R = DM; C = 3 * DM;
                          int ix = bid - 1024; bx = ix % 48; by = ix / 48; }
        else            { src = wo; dst = woT; R = DM; C = DM;
                          int ix = bid - 1792; bx = ix & 15; by = ix >> 4; }
        int x0 = bx << 5, y0 = by << 5;
        int tx = tid & 31, ty = tid >> 5;
#pragma unroll
        for (int i = 0; i < 4; ++i)
            tile[ty + i * 8][tx] = src[(size_t)(y0 + ty + i * 8) * C + x0 + tx];
        __syncthreads();
#pragma unroll
        for (int i = 0; i < 4; ++i)
            dst[(size_t)(x0 + ty + i * 8) * R + y0 + tx] = f2bf(tile[tx][ty + i * 8]);
    } else {
        int item = (bid - 2048) * 256 + tid;
        int p   = item & 31;
        int idx = item >> 5;                // h*NSEQ + t, < 16384
        int h = idx >> 11;
        int t = idx & (NSEQ - 1);
        float scale = expf(ls[h]);
        float tau = log1pf((float)t);
        const float TAUF = 6.2831853071795864769f;
        float g  = RZF[p] / RZF[0];
        float th = (tau * g) * scale;
        cosT[(size_t)idx * KP + p] = cosf(th);
        sinT[(size_t)idx * KP + p] = sinf(th);
        float fl = floorf(th / TAUF);
        fl += __shfl_xor(fl, 1);
        fl += __shfl_xor(fl, 2);
        fl += __shfl_xor(fl, 4);
        fl += __shfl_xor(fl, 8);
        fl += __shfl_xor(fl, 16);
        if (p == 0) biasK[idx] = expf(ll[h]) * (1.0f / 32.0f) * fl * LOG2E;
    }
}

// ---------------------------------------------------------------------------
// K2: MFMA GEMM  xb @ wqT^T, fused rotation epilogue. BM=64, BN=128 ->
// 768 blocks = 3/CU, double-buffered issue-early staging (r14-proven).
// q_rot pre-scaled 0.125*log2e; V -> transposed [b][h][dh][n].
// ---------------------------------------------------------------------------
__global__ __launch_bounds__(256) void k_gemm_qkv(
    const unsigned short* __restrict__ xb, const unsigned short* __restrict__ wt,
    const float* __restrict__ cosT, const float* __restrict__ sinT,
    unsigned short* __restrict__ qrot, unsigned short* __restrict__ krot,
    unsigned short* __restrict__ vtout)
{
    __shared__ char Asm[2][64 * 128];    // 8 KB x2
    __shared__ char Bsm[2][128 * 128];   // 16 KB x2
    int tid = threadIdx.x;
    int w = tid >> 6, lane = tid & 63, g = lane >> 4, c = lane & 15;
    int wm = w >> 1, wn = w & 1;
    int bm = blockIdx.y << 6, bn = blockIdx.x << 7;
    int rin = lane >> 3;
    int csw = ((lane & 7) ^ rin) << 4;

    f32x4 acc[2][4];
#pragma unroll
    for (int mi = 0; mi < 2; ++mi)
#pragma unroll
        for (int ni = 0; ni < 4; ++ni) acc[mi][ni] = (f32x4){0.f, 0.f, 0.f, 0.f};

    const char* Ag = (const char*)xb;
    const char* Bg = (const char*)wt;

    auto stage = [&](int buf, int k0) {
#pragma unroll
        for (int ch = 0; ch < 2; ++ch) {            // A: 8 chunks (64 rows)
            int chA = w * 2 + ch;
            int row = chA * 8 + rin;
            gload16(Ag + ((size_t)(bm + row) * DM + k0) * 2 + csw, Asm[buf] + chA * 1024);
        }
#pragma unroll
        for (int ch = 0; ch < 4; ++ch) {            // B: 16 chunks (128 rows)
            int chB = w * 4 + ch;
            int row = chB * 8 + rin;
            gload16(Bg + ((size_t)(bn + row) * DM + k0) * 2 + csw, Bsm[buf] + chB * 1024);
        }
    };

    stage(0, 0);
    asm volatile("s_waitcnt vmcnt(0)" ::: "memory");
    __syncthreads();
    int cur = 0;

    for (int k0 = 0; k0 < DM; k0 += 64) {
        if (k0 + 64 < DM) stage(cur ^ 1, k0 + 64);   // issue-early
#pragma unroll
        for (int kk = 0; kk < 2; ++kk) {
            bf16x8 af[2], bfr[4];
#pragma unroll
            for (int mi = 0; mi < 2; ++mi) {
                int row = wm * 32 + mi * 16 + c;
                af[mi] = *(const bf16x8*)(Asm[cur] + ((row * 128 + kk * 64 + g * 16) ^ ((row & 7) << 4)));
            }
#pragma unroll
            for (int ni = 0; ni < 4; ++ni) {
                int row = wn * 64 + ni * 16 + c;
                bfr[ni] = *(const bf16x8*)(Bsm[cur] + ((row * 128 + kk * 64 + g * 16) ^ ((row & 7) << 4)));
            }
#pragma unroll
            for (int mi = 0; mi < 2; ++mi)
#pragma unroll
                for (int ni = 0; ni < 4; ++ni)
                    acc[mi][ni] = __builtin_amdgcn_mfma_f32_16x16x32_bf16(
                        af[mi], bfr[ni], acc[mi][ni], 0, 0, 0);
        }
        asm volatile("s_waitcnt vmcnt(0)" ::: "memory");   // drain next-tile DMA
        __syncthreads();
        cur ^= 1;
    }

    int lane_odd = c & 1;
#pragma unroll
    for (int ni = 0; ni < 4; ++ni) {
        int n = bn + wn * 64 + ni * 16 + c;
        int sec = n >> 9;               // 0=q 1=k 2=v
        int dmod = n & 511;
        int h = dmod >> 6, dh = dmod & 63, p = dh >> 1;
        if (sec == 2) {
#pragma unroll
            for (int mi = 0; mi < 2; ++mi) {
                int m0 = bm + wm * 32 + mi * 16 + g * 4;
                int b = m0 >> 11, t0 = m0 & (NSEQ - 1);
                union { unsigned short s[4]; uint2 u; } pk;
                pk.s[0] = f2bf(acc[mi][ni][0]); pk.s[1] = f2bf(acc[mi][ni][1]);
                pk.s[2] = f2bf(acc[mi][ni][2]); pk.s[3] = f2bf(acc[mi][ni][3]);
                *(uint2*)(vtout + ((size_t)(b * NH + h) * DH + dh) * NSEQ + t0) = pk.u;
            }
        } else {
            const float* cb_ = cosT + (size_t)h * NSEQ * KP + p;
            const float* sb_ = sinT + (size_t)h * NSEQ * KP + p;
            unsigned short* dst = (sec == 0) ? qrot : krot;
            float osc = (sec == 0) ? (0.125f * LOG2E) : 1.0f;   // exp2-domain scale
#pragma unroll
            for (int mi = 0; mi < 2; ++mi) {
#pragma unroll
                for (int r = 0; r < 4; ++r) {
                    int m = bm + wm * 32 + mi * 16 + g * 4 + r;
                    int b = m >> 11, t = m & (NSEQ - 1);
                    float val = acc[mi][ni][r];
                    float pv = __shfl_xor(val, 1);
                    float cv = cb_[(size_t)t * KP], sv = sb_[(size_t)t * KP];
                    float o = lane_odd ? (pv * sv + val * cv) : (val * cv - pv * sv);
                    dst[((size_t)(b * NH + h) * NSEQ + t) * DH + dh] = f2bf(o * osc);
                }
            }
        }
    }
}

// ---------------------------------------------------------------------------
// K3: split-K MFMA flash attention (r12/r14-proven structure: K AND V staged
// via LDS DMA — V-in-registers refuted twice by compiler scheduling).
// QBLK=64, 4-tile chunks, 2304 blocks, XCD bh mapping, heavy-first,
// cvt_pk P-packing, exp2-domain softmax.
// ---------------------------------------------------------------------------
__global__ __launch_bounds__(256) void k_attn(
    const unsigned short* __restrict__ qr, const unsigned short* __restrict__ kr,
    const unsigned short* __restrict__ vt, const float* __restrict__ biasK,
    unsigned short* __restrict__ ao, unsigned short* __restrict__ opart,
    float* __restrict__ mlpart)
{
    __shared__ char Kbuf[8192];                 // [key][dh] bf16, row-swizzled
    __shared__ char Vbuf[8192];                 // [d][key]  bf16, row-swizzled
    __shared__ char Pl[4][2048];                // per-wave [16 q][64 key] bf16
    __shared__ float Bk[64];

    int bid = blockIdx.x;
    int xcd = bid & 7;
    int i   = bid >> 3;             // 0..287
    int bh  = xcd * 2 + (i & 1);
    int slot = (SLOT4 - 1) - (i >> 1);          // heavy-first 0..143
    int b = bh >> 3, h = bh & 7;
    int s = slot, qt = 0, nch;
    for (;;) { nch = (qt + 4) >> 2; if (s < nch) break; s -= nch; ++qt; }
    int ci = s;
    int t0 = ci << 2;
    int t1 = min(t0 + 4, qt + 1);

    int q0 = qt << 6;
    int tid = threadIdx.x;
    int w    = tid >> 6;
    int lane = tid & 63;
    int g    = lane >> 4;
    int c    = lane & 15;
    char* Pb = Pl[w];

    const char* kb  = (const char*)(kr + (size_t)bh * NSEQ * DH);
    const char* vtb = (const char*)(vt + (size_t)bh * DH * NSEQ);
    const unsigned short* qb = qr + (size_t)bh * NSEQ * DH;
    const float* bkrow = biasK + (size_t)h * NSEQ;

    int qg = q0 + (w << 4) + c;     // this lane's softmax row (q = c)

    bf16x8 qf[2];
#pragma unroll
    for (int sl = 0; sl < 2; ++sl)
        qf[sl] = *(const bf16x8*)(qb + (size_t)qg * DH + sl * 32 + g * 8);

    f32x4 oa[4];
#pragma unroll
    for (int dt = 0; dt < 4; ++dt) oa[dt] = (f32x4){0.f, 0.f, 0.f, 0.f};
    float mr = -3.0e38f, lr = 0.0f;

    int rin = lane >> 3;
    int swz = ((lane & 7) ^ rin) << 4;          // pre-swizzled source byte-col

    for (int tile = t0; tile < t1; ++tile) {
        int j0 = tile << 6;
        // ---- stage K / V^T / bias (single buffer) ----
#pragma unroll
        for (int ii = 0; ii < 2; ++ii) {
            int ch = w * 2 + ii;
            int row = ch * 8 + rin;
            gload16(kb  + (size_t)(j0 + row) * 128 + swz, Kbuf + ch * 1024);
            gload16(vtb + (size_t)row * (NSEQ * 2) + (size_t)j0 * 2 + swz,
                    Vbuf + ch * 1024);
        }
        if (tid < 64) Bk[tid] = bkrow[j0 + tid];
        asm volatile("s_waitcnt vmcnt(0)" ::: "memory");   // explicit DMA drain
        __syncthreads();

        // ---- S^T = K · Q^T  (q pre-scaled by 0.125*log2e) ----
        f32x4 st[4];
#pragma unroll
        for (int kt = 0; kt < 4; ++kt) st[kt] = (f32x4){0.f, 0.f, 0.f, 0.f};
#pragma unroll
        for (int sl = 0; sl < 2; ++sl) {
#pragma unroll
            for (int kt = 0; kt < 4; ++kt) {
                int row = kt * 16 + c;
                bf16x8 af = *(const bf16x8*)(Kbuf +
                    ((row * 128 + sl * 64 + g * 16) ^ ((row & 7) << 4)));
                st[kt] = __builtin_amdgcn_mfma_f32_16x16x32_bf16(af, qf[sl], st[kt], 0, 0, 0);
            }
        }

        // ---- bias + causal mask (log2 domain) ----
        bool diagT = (tile == qt);
        float sv[16];
#pragma unroll
        for (int kt = 0; kt < 4; ++kt) {
#pragma unroll
            for (int r4 = 0; r4 < 4; ++r4) {
                int ki = kt * 16 + g * 4 + r4;
                float vl = st[kt][r4] + Bk[ki];
                if (diagT && (j0 + ki > qg)) vl = -3.0e38f;
                sv[kt * 4 + r4] = vl;
            }
        }

        // ---- online softmax, exp2 domain, defer-max (11.5 bits = 8 nats) ----
        float m16 = sv[0];
#pragma unroll
        for (int ii = 1; ii < 16; ++ii) m16 = fmaxf(m16, sv[ii]);
        m16 = fmaxf(m16, __shfl_xor(m16, 16));
        m16 = fmaxf(m16, __shfl_xor(m16, 32));
        if (__any(m16 > mr + 11.5f)) {
            float mt = fmaxf(mr, m16);
            float corr = exp2q(mr - mt);
            mr = mt;
            lr *= corr;
            float corrO[4];
#pragma unroll
            for (int r4 = 0; r4 < 4; ++r4) corrO[r4] = __shfl(corr, g * 4 + r4);
#pragma unroll
            for (int dt = 0; dt < 4; ++dt)
#pragma unroll
                for (int r4 = 0; r4 < 4; ++r4) oa[dt][r4] *= corrO[r4];
        }
        float psum = 0.0f;
        unsigned int pw[8];
#pragma unroll
        for (int ii = 0; ii < 8; ++ii) {
            float p0 = exp2q(sv[2 * ii]     - mr);
            float p1 = exp2q(sv[2 * ii + 1] - mr);
            psum += p0 + p1;
            asm("v_cvt_pk_bf16_f32 %0, %1, %2" : "=v"(pw[ii]) : "v"(p0), "v"(p1));
        }
        lr += psum;

        // ---- P (bf16) -> per-wave LDS: [q=c][key] ----
#pragma unroll
        for (int kt = 0; kt < 4; ++kt) {
            uint2 u2; u2.x = pw[2 * kt]; u2.y = pw[2 * kt + 1];
            *(uint2*)(Pb + ((c * 128 + kt * 32 + g * 8) ^ ((c & 7) << 4))) = u2;
        }

        // ---- O += P · V ----
#pragma unroll
        for (int sl = 0; sl < 2; ++sl) {
            bf16x8 pa = *(const bf16x8*)(Pb + ((c * 128 + sl * 64 + g * 16) ^ ((c & 7) << 4)));
#pragma unroll
            for (int dt = 0; dt < 4; ++dt) {
                int d = dt * 16 + c;
                bf16x8 vf = *(const bf16x8*)(Vbuf +
                    ((d * 128 + sl * 64 + g * 16) ^ ((d & 7) << 4)));
                oa[dt] = __builtin_amdgcn_mfma_f32_16x16x32_bf16(pa, vf, oa[dt], 0, 0, 0);
            }
        }
        __syncthreads();   // all waves done reading before next stage overwrites
    }

    // ---- epilogue: reduce l; lane holds O[q=g*4+r4][d=dt*16+c] ----
    lr += __shfl_xor(lr, 16);
    lr += __shfl_xor(lr, 32);
    if (nch == 1) {     // qt 0..3: single chunk -> final normalized output
        float inv = 1.0f / lr;
        float invO[4];
#pragma unroll
        for (int r4 = 0; r4 < 4; ++r4) invO[r4] = __shfl(inv, g * 4 + r4);
#pragma unroll
        for (int dt = 0; dt < 4; ++dt)
#pragma unroll
            for (int r4 = 0; r4 < 4; ++r4) {
                int row = q0 + (w << 4) + g * 4 + r4;
                ao[((size_t)b * NSEQ + row) * DM + h * DH + dt * 16 + c] =
                    f2bf(oa[dt][r4] * invO[r4]);
            }
    } else {
        size_t obase = ((size_t)bh * SLOT4 + slot) * (64 * 64);
#pragma unroll
        for (int dt = 0; dt < 4; ++dt)
#pragma unroll
            for (int r4 = 0; r4 < 4; ++r4) {
                int row = (w << 4) + g * 4 + r4;     // row within block
                opart[obase + row * 64 + dt * 16 + c] = f2bf(oa[dt][r4]);
            }
        if (g == 0) {   // row = w*16 + c  (mr in log2 domain -> merge uses exp2)
            size_t mb = (((size_t)bh * SLOT4 + slot) * 64 + (w << 4) + c) * 2;
            mlpart[mb]     = mr;
            mlpart[mb + 1] = lr;
        }
    }
}

// ---------------------------------------------------------------------------
// K3b: phase-2 merge for qt >= 4 (2..8 chunks). Grid (28, 16bh), 256 thr.
// m values in log2 domain -> weights use exp2.
// ---------------------------------------------------------------------------
__global__ __launch_bounds__(256) void k_merge(
    const unsigned short* __restrict__ opart, const float* __restrict__ mlpart,
    unsigned short* __restrict__ ao)
{
    int bh = blockIdx.y;
    int b = bh >> 3, h = bh & 7;
    int qt = 4 + blockIdx.x;              // 4..31
    int nch = (qt + 4) >> 2;              // 2..8
    int slot0 = 0;
    for (int q = 0; q < qt; ++q) slot0 += (q + 4) >> 2;
    int tid = threadIdx.x;
    int row = tid >> 2;                   // 0..63
    int d0 = (tid & 3) << 4;              // 0,16,32,48

    size_t pbase = ((size_t)bh * SLOT4 + slot0) * 4096 + row * 64 + d0;
    size_t mbase = (((size_t)bh * SLOT4 + slot0) * 64 + row) * 2;

    float M = -3.0e38f;
#pragma unroll
    for (int cc = 0; cc < 8; ++cc)
        if (cc < nch) M = fmaxf(M, mlpart[mbase + (size_t)cc * 128]);

    float L = 0.0f;
    float o[16];
#pragma unroll
    for (int ii = 0; ii < 16; ++ii) o[ii] = 0.0f;
#pragma unroll
    for (int cc = 0; cc < 8; ++cc) {
        if (cc < nch) {
            float mc = mlpart[mbase + (size_t)cc * 128];
            float lc = mlpart[mbase + (size_t)cc * 128 + 1];
            float wgt = exp2f(mc - M);
            L += lc * wgt;
            union { uint4 u; unsigned short sh[8]; } lo, hi;
            lo.u = *(const uint4*)(opart + pbase + (size_t)cc * 4096);
            hi.u = *(const uint4*)(opart + pbase + (size_t)cc * 4096 + 8);
#pragma unroll
            for (int ii = 0; ii < 8; ++ii) {
                o[ii]     += bf2f(lo.sh[ii]) * wgt;
                o[ii + 8] += bf2f(hi.sh[ii]) * wgt;
            }
        }
    }
    float invL = 1.0f / L;
    int grow = (qt << 6) + row;
    unsigned short* dst = ao + ((size_t)b * NSEQ + grow) * DM + h * DH + d0;
    union { unsigned short sh[8]; uint4 u; } p0, p1;
#pragma unroll
    for (int ii = 0; ii < 8; ++ii) {
        p0.sh[ii] = f2bf(o[ii] * invL);
        p1.sh[ii] = f2bf(o[ii + 8] * invL);
    }
    *(uint4*)dst = p0.u;
    *(uint4*)(dst + 8) = p1.u;
}

// ---------------------------------------------------------------------------
// K4: MFMA GEMM  aob(4096x512 bf16) @ woT^T -> f32 out.
// BM=64, BN=64 -> 512 blocks = 2/CU. Waves 2x2, each 32x32.
// ---------------------------------------------------------------------------
__global__ __launch_bounds__(256) void k_gemm_out(
    const unsigned short* __restrict__ aob, const unsigned short* __restrict__ wt,
    float* __restrict__ out)
{
    __shared__ char Asm[64 * 128];    // 8 KB
    __shared__ char Bsm[64 * 128];    // 8 KB
    int tid = threadIdx.x;
    int w = tid >> 6, lane = tid & 63, g = lane >> 4, c = lane & 15;
    int wm = w >> 1, wn = w & 1;
    int bm = blockIdx.y << 6, bn = blockIdx.x << 6;
    int rin = lane >> 3;
    int csw = ((lane & 7) ^ rin) << 4;

    f32x4 acc[2][2];
#pragma unroll
    for (int mi = 0; mi < 2; ++mi)
#pragma unroll
        for (int ni = 0; ni < 2; ++ni) acc[mi][ni] = (f32x4){0.f, 0.f, 0.f, 0.f};

    const char* Ag = (const char*)aob;
    const char* Bg = (const char*)wt;

    for (int k0 = 0; k0 < DM; k0 += 64) {
        __syncthreads();
#pragma unroll
        for (int ch = 0; ch < 2; ++ch) {            // A: 8 chunks (64 rows)
            int chA = w * 2 + ch;
            int row = chA * 8 + rin;
            gload16(Ag + ((size_t)(bm + row) * DM + k0) * 2 + csw, Asm + chA * 1024);
        }
#pragma unroll
        for (int ch = 0; ch < 2; ++ch) {            // B: 8 chunks (64 rows)
            int chB = w * 2 + ch;
            int row = chB * 8 + rin;
            gload16(Bg + ((size_t)(bn + row) * DM + k0) * 2 + csw, Bsm + chB * 1024);
        }
        asm volatile("s_waitcnt vmcnt(0)" ::: "memory");
        __syncthreads();
#pragma unroll
        for (int kk = 0; kk < 2; ++kk) {
            bf16x8 af[2], bfr[2];
#pragma unroll
            for (int mi = 0; mi < 2; ++mi) {
                int row = wm * 32 + mi * 16 + c;
                af[mi] = *(const bf16x8*)(Asm + ((row * 128 + kk * 64 + g * 16) ^ ((row & 7) << 4)));
            }
#pragma unroll
            for (int ni = 0; ni < 2; ++ni) {
                int row = wn * 32 + ni * 16 + c;
                bfr[ni] = *(const bf16x8*)(Bsm + ((row * 128 + kk * 64 + g * 16) ^ ((row & 7) << 4)));
            }
#pragma unroll
            for (int mi = 0; mi < 2; ++mi)
#pragma unroll
                for (int ni = 0; ni < 2; ++ni)
                    acc[mi][ni] = __builtin_amdgcn_mfma_f32_16x16x32_bf16(
                        af[mi], bfr[ni], acc[mi][ni], 0, 0, 0);
        }
    }

#pragma unroll
    for (int ni = 0; ni < 2; ++ni) {
        int n = bn + wn * 32 + ni * 16 + c;
#pragma unroll
        for (int mi = 0; mi < 2; ++mi)
#pragma unroll
            for (int r = 0; r < 4; ++r) {
                int m = bm + wm * 32 + mi * 16 + g * 4 + r;
                out[(size_t)m * DM + n] = acc[mi][ni][r];
            }
    }
}

// ---------------------------------------------------------------------------
extern "C" void kernel_launch(void* const* d_in, const int* in_sizes, int n_in,
                              void* d_out, int out_size, void* d_ws, size_t ws_size,
                              hipStream_t stream)
{
    const float* x  = (const float*)d_in[0];
    const float* wq = (const float*)d_in[1];
    const float* wo = (const float*)d_in[2];
    const float* ls = (const float*)d_in[3];
    const float* ll = (const float*)d_in[4];
    float* out = (float*)d_out;

    char* ws = (char*)d_ws;
    size_t off = 0;
    float* cosT  = (float*)(ws + off); off += (size_t)NH * NSEQ * KP * 4;        // 2 MB
    float* sinT  = (float*)(ws + off); off += (size_t)NH * NSEQ * KP * 4;        // 2 MB
    float* biasK = (float*)(ws + off); off += (size_t)NH * NSEQ * 4;             // 64 KB
    unsigned short* xb  = (unsigned short*)(ws + off); off += (size_t)MROWS * DM * 2;      // 4 MB
    unsigned short* wqT = (unsigned short*)(ws + off); off += (size_t)DM * 3 * DM * 2;     // 1.5 MB
    unsigned short* woT = (unsigned short*)(ws + off); off += (size_t)DM * DM * 2;         // 0.5 MB
    unsigned short* qbf = (unsigned short*)(ws + off); off += (size_t)MROWS * DM * 2;      // 4 MB
    unsigned short* kbf = (unsigned short*)(ws + off); off += (size_t)MROWS * DM * 2;      // 4 MB
    unsigned short* vtb = (unsigned short*)(ws + off); off += (size_t)MROWS * DM * 2;      // 4 MB
    unsigned short* aob = (unsigned short*)(ws + off); off += (size_t)MROWS * DM * 2;      // 4 MB
    unsigned short* opart = (unsigned short*)(ws + off);
    off += (size_t)NB * NH * SLOT4 * 64 * 64 * 2;                                // 18.9 MB
    float* mlpart = (float*)(ws + off); off += (size_t)NB * NH * SLOT4 * 64 * 2 * 4; // 1.2 MB

    k_prep<<<4096, 256, 0, stream>>>(x, wq, wo, ls, ll, xb, wqT, woT, cosT, sinT, biasK);
    k_gemm_qkv<<<dim3(3 * DM / 128, MROWS / 64), 256, 0, stream>>>(
        xb, wqT, cosT, sinT, qbf, kbf, vtb);
    k_attn<<<8 * 288, 256, 0, stream>>>(
        qbf, kbf, vtb, biasK, aob, opart, mlpart);
    k_merge<<<dim3(28, NB * NH), 256, 0, stream>>>(opart, mlpart, aob);
    k_gemm_out<<<dim3(DM / 64, MROWS / 64), 256, 0, stream>>>(aob, woT, out);
}